// Round 7
// baseline (24.960 us; speedup 1.0000x reference)
//
#include <hip/hip_runtime.h>
#include <math.h>

namespace {
constexpr int   KMAX   = 12;
constexpr int   NLINE  = 313;                    // half-space (h,k) lines
constexpr int   NGROUP = NLINE * 5;              // 1565 l-groups of 5
constexpr int   NKV    = NGROUP * 5;             // 7825 computed k-vecs (13 masked)
constexpr int   NSLICE = 8;                      // particle slices
constexpr int   S2_BLOCKS = (NKV + 255) / 256;   // 31
constexpr float ALPHA_  = 0.34f;
constexpr float TWO_PI_ = 6.283185307179586f;
}

__device__ __forceinline__ void cofactors(const float* __restrict__ box,
                                          float C[3][3], float* det) {
  const float b00 = box[0], b01 = box[1], b02 = box[2];
  const float b10 = box[3], b11 = box[4], b12 = box[5];
  const float b20 = box[6], b21 = box[7], b22 = box[8];
  C[0][0] =  (b11 * b22 - b12 * b21);
  C[0][1] = -(b10 * b22 - b12 * b20);
  C[0][2] =  (b10 * b21 - b11 * b20);
  C[1][0] = -(b01 * b22 - b02 * b21);
  C[1][1] =  (b00 * b22 - b02 * b20);
  C[1][2] = -(b00 * b21 - b01 * b20);
  C[2][0] =  (b01 * b12 - b02 * b11);
  C[2][1] = -(b00 * b12 - b02 * b10);
  C[2][2] =  (b00 * b11 - b01 * b10);
  *det = b00 * C[0][0] + b01 * C[0][1] + b02 * C[0][2];
}

// Half-space lines: L<300: h=1..12 x k=-12..12; L=300..311: h=0,k=1..12; L=312: h=k=0.
__device__ __forceinline__ void line_hk(int L, int* h, int* k) {
  if (L < 300)      { *h = L / 25 + 1; *k = L % 25 - 12; }
  else if (L < 312) { *h = 0;          *k = L - 299;     }
  else              { *h = 0;          *k = 0;           }
}

// Pre-kernel: fractional coords + charge, one float4 per particle; zeroes out[0].
__global__ __launch_bounds__(256) void make_frac(
    const float* __restrict__ coords, const float* __restrict__ box,
    const float* __restrict__ q, int N, float4* __restrict__ frac,
    float* __restrict__ out)
{
  const int i = blockIdx.x * 256 + threadIdx.x;
  if (i == 0) out[0] = 0.0f;   // atomic target for stage2 (stream-ordered)
  if (i >= N) return;
  float C[3][3], det;
  cofactors(box, C, &det);
  const float invdet = 1.0f / det;
  const float x = coords[3 * i + 0];
  const float y = coords[3 * i + 1];
  const float z = coords[3 * i + 2];
  float4 f;
  f.x = (x * C[0][0] + y * C[0][1] + z * C[0][2]) * invdet;   // a
  f.y = (x * C[1][0] + y * C[1][1] + z * C[1][2]) * invdet;   // b
  float c = (x * C[2][0] + y * C[2][1] + z * C[2][2]) * invdet;
  f.z = c - floorf(c);                                        // c in [0,1)
  f.w = q[i];
  frac[i] = f;
}

// One wave = one l-group (5 l of one (h,k) line) x one particle slice.
// Lean: no LDS, no barriers, no box math -> low VGPR -> 8 waves/SIMD.
__global__ __launch_bounds__(256, 8) void ewald_g5(
    const float4* __restrict__ frac, int N, float* __restrict__ partial)
{
  const int lane = threadIdx.x & 63;
  const int g    = blockIdx.x * 4 + (threadIdx.x >> 6);
  const int gc   = (g < NGROUP) ? g : (NGROUP - 1);  // clamp for decode; store guarded

  int h, k; line_hk(gc / 5, &h, &k);
  const float hf  = (float)h;
  const float kf  = (float)k;
  const float l0f = (float)(-KMAX + 5 * (gc % 5));

  const int slice = blockIdx.y;
  const int sp    = (N + NSLICE - 1) / NSLICE;
  const int s_beg = slice * sp;
  const int s_end = min(s_beg + sp, N);

  float Sre[5] = {0.f, 0.f, 0.f, 0.f, 0.f};
  float Sim[5] = {0.f, 0.f, 0.f, 0.f, 0.f};

  for (int i = s_beg + lane; i < s_end; i += 64) {
    const float4 p = frac[i];                            // coalesced 16B, L1/L2-hot
    float t = fmaf(hf, p.x, fmaf(kf, p.y, l0f * p.z));   // phase(l0) in revolutions
    float tf;
    asm("v_fract_f32 %0, %1" : "=v"(tf) : "v"(t));
    float s0, c0, sr, cr;
    asm("v_sin_f32 %0, %1" : "=v"(s0) : "v"(tf));
    asm("v_cos_f32 %0, %1" : "=v"(c0) : "v"(tf));
    asm("v_sin_f32 %0, %1" : "=v"(sr) : "v"(p.z));       // rotator e^{i*2pi*c}
    asm("v_cos_f32 %0, %1" : "=v"(cr) : "v"(p.z));
    float Pre = p.w * c0, Pim = p.w * s0;                // q folded into phasor
    Sre[0] += Pre; Sim[0] += Pim;
#pragma unroll
    for (int u = 1; u < 5; ++u) {
      const float nre = fmaf(Pre, cr, -(Pim * sr));
      const float nim = fmaf(Pre, sr,  (Pim * cr));
      Pre = nre; Pim = nim;
      Sre[u] += Pre; Sim[u] += Pim;
    }
  }

#pragma unroll
  for (int off = 32; off > 0; off >>= 1) {
#pragma unroll
    for (int u = 0; u < 5; ++u) {
      Sre[u] += __shfl_down(Sre[u], off);
      Sim[u] += __shfl_down(Sim[u], off);
    }
  }
  if (g < NGROUP && lane == 0) {
    float* dst = partial + (size_t)(g * NSLICE + slice) * 10;
#pragma unroll
    for (int u = 0; u < 5; ++u) {
      dst[2 * u + 0] = Sre[u];
      dst[2 * u + 1] = Sim[u];
    }
  }
}

// Sum slices, square, weight by fac, scale by 4*pi/V; one atomicAdd per block.
__global__ __launch_bounds__(256) void stage2(
    const float* __restrict__ partial, const float* __restrict__ box,
    float* __restrict__ out)
{
  __shared__ float red[256];
  const int idx = blockIdx.x * 256 + threadIdx.x;
  float e = 0.f;
  if (idx < NKV) {
    const int g = idx / 5, u = idx % 5;
    const int L = g / 5, sub = g % 5;
    int h, k; line_hk(L, &h, &k);
    const int l = -KMAX + 5 * sub + u;
    if (!(h == 0 && k == 0 && l <= 0)) {   // mask the 13 non-half-space entries
      float re = 0.f, im = 0.f;
      for (int s = 0; s < NSLICE; ++s) {
        const float* p = partial + (size_t)(g * NSLICE + s) * 10 + 2 * u;
        re += p[0]; im += p[1];
      }
      float C[3][3], det;
      cofactors(box, C, &det);
      const float invdet = 1.0f / det;
      const float hf = (float)h, kf = (float)k, lf = (float)l;
      const float kx = (hf * C[0][0] + kf * C[1][0] + lf * C[2][0]) * invdet;
      const float ky = (hf * C[0][1] + kf * C[1][1] + lf * C[2][1]) * invdet;
      const float kz = (hf * C[0][2] + kf * C[1][2] + lf * C[2][2]) * invdet;
      const float k2 = TWO_PI_ * TWO_PI_ * (kx * kx + ky * ky + kz * kz);
      const float fac = __expf(-k2 / (4.0f * ALPHA_ * ALPHA_)) / k2;
      e = fac * fmaf(re, re, im * im);
    }
  }
  red[threadIdx.x] = e;
  __syncthreads();
  for (int s = 128; s > 0; s >>= 1) {
    if (threadIdx.x < s) red[threadIdx.x] += red[threadIdx.x + s];
    __syncthreads();
  }
  if (threadIdx.x == 0) {
    float C[3][3], det;
    cofactors(box, C, &det);
    // E = (2*pi/V)*full_sum = (4*pi/V)*half_sum
    const float scale = (4.0f * 3.14159265358979323846f) / fabsf(det);
    atomicAdd(out, scale * red[0]);
  }
}

extern "C" void kernel_launch(void* const* d_in, const int* in_sizes, int n_in,
                              void* d_out, int out_size, void* d_ws, size_t ws_size,
                              hipStream_t stream) {
  const float* coords = (const float*)d_in[0];
  const float* box    = (const float*)d_in[1];
  const float* q      = (const float*)d_in[2];
  float* out = (float*)d_out;
  const int N = in_sizes[2];

  // ws: [0, N*16B) float4 frac table; [128 KiB, +500,800 B) partial S factors
  float4* frac    = (float4*)d_ws;
  float*  partial = (float*)((char*)d_ws + (128 << 10));

  hipLaunchKernelGGL(make_frac, dim3((N + 255) / 256), dim3(256), 0, stream,
                     coords, box, q, N, frac, out);
  const dim3 grid((NGROUP + 3) / 4, NSLICE);   // 392 x 8 = 3136 blocks
  hipLaunchKernelGGL(ewald_g5, grid, dim3(256), 0, stream, frac, N, partial);
  hipLaunchKernelGGL(stage2, dim3(S2_BLOCKS), dim3(256), 0, stream,
                     partial, box, out);
}